// Round 1
// 610.833 us; speedup vs baseline: 1.2922x; 1.2922x over previous
//
#include <hip/hip_runtime.h>
#include <cstddef>

// DeformLayer on MI355X. Round 4: attack latency-bound MFMA kernels
// (deform 300us @ 5% MfmaUtil / 10% VALU / 2 barriers-per-iter serial chain).
//  - k_tr_x: one-time fp32 transpose x -> xt[b][c/32][pix][32ch] so bilinear
//    corners load 8 channels as 2x float4 (VMEM instrs per iter 32 -> 8).
//    xt lives in the 'up' output region (written only by the final kernel).
//  - k_deform_mfma / k_deconv_mfma: double-buffered LDS, ONE barrier per
//    K-iter; next-iter gathers + A-tile load_lds issued BEFORE this iter's
//    MFMA, packed/written after (T14 async-stage split). cpk quads preloaded;
//    inner chunk loop unrolled so all reg-array indices are compile-time.
// Offset conv / prep kernels unchanged from R3.

#define B_EPS 1e-5f

typedef __bf16 bf16x8 __attribute__((ext_vector_type(8)));
typedef float f32x4 __attribute__((ext_vector_type(4)));
typedef unsigned short u16;
typedef unsigned int u32;

__device__ __forceinline__ u32 bfr(float f) {          // fp32 -> bf16 bits (RNE)
    u32 u = __float_as_uint(f);
    return (u + 0x7FFFu + ((u >> 16) & 1u)) >> 16;
}

__device__ __forceinline__ void load_lds16(const void* g, void* l) {
    __builtin_amdgcn_global_load_lds(
        (const __attribute__((address_space(1))) unsigned int*)g,
        (__attribute__((address_space(3))) unsigned int*)l, 16, 0, 0);
}

// ---------------- tiny prep kernels ----------------
// w_off[27][256][9] -> wofft[c][co*9+t] (uniform scalar loads in offset conv)
__global__ __launch_bounds__(256) void k_tr_woff(const float* __restrict__ w,
                                                 float* __restrict__ o) {
    int i = blockIdx.x * 256 + threadIdx.x;      // 62208
    int t9 = i % 9; int r = i / 9; int c = r & 255; int co = r >> 8;
    o[c * 243 + co * 9 + t9] = w[i];
}

// w_dcn[o][c][9] -> Wdb[k][cc][o][40] bf16 (frag-ready A tiles, kk=c within chunk)
__global__ __launch_bounds__(256) void k_prep_wdb(const float* __restrict__ w,
                                                  u16* __restrict__ o) {
    int i = blockIdx.x * 256 + threadIdx.x;      // 737280 = 2880*256
    int kk = i % 40; int e = i / 40;
    int oc = e & 255; e >>= 8;
    int cc = e & 7; int k = e >> 3;
    float v = (kk < 32) ? w[oc * 2304 + (cc * 32 + kk) * 9 + k] : 0.f;
    o[i] = (u16)bfr(v);
}

// w_up[ci][co][wr][wc] -> Wtb[cls][cc][o][40] bf16, kk = ci_l*4 + tap
__global__ __launch_bounds__(256) void k_prep_wtb(const float* __restrict__ w,
                                                  u16* __restrict__ o) {
    int i = blockIdx.x * 256 + threadIdx.x;      // 1310720 = 5120*256
    int kk = i % 40; int e = i / 40;
    int oc = e & 255; e >>= 8;
    int cc = e & 31; int cls = e >> 5;
    float v = 0.f;
    if (kk < 32) {
        int ci = cc * 8 + (kk >> 2), tap = kk & 3;
        int ca = cls >> 1, cb = cls & 1;
        int wr = (tap >> 1) ? (ca ? 0 : 1) : (ca ? 2 : 3);
        int wc = (tap & 1) ? (cb ? 0 : 1) : (cb ? 2 : 3);
        v = w[ci * 4096 + oc * 16 + wr * 4 + wc];
    }
    o[i] = (u16)bfr(v);
}

// folded BN params: bnp = [sc1|bi1|sc2|bi2], 4x256 floats
__global__ __launch_bounds__(256) void k_bn_prep(
    const float* g1, const float* be1, const float* mu1, const float* va1,
    const float* g2, const float* be2, const float* mu2, const float* va2,
    float* bnp) {
    int t = threadIdx.x;
    float s1 = g1[t] * rsqrtf(va1[t] + B_EPS);
    bnp[t] = s1; bnp[256 + t] = be1[t] - mu1[t] * s1;
    float s2 = g2[t] * rsqrtf(va2[t] + B_EPS);
    bnp[512 + t] = s2; bnp[768 + t] = be2[t] - mu2[t] * s2;
}

// om init: om[b][27][4096] = b_off[co]  (atomic accumulation base)
__global__ __launch_bounds__(256) void k_om_init(const float* __restrict__ b_off,
                                                 float* __restrict__ om) {
    int i = blockIdx.x * 256 + threadIdx.x;      // 884736 = 3456*256
    int co = (i >> 12) % 27;
    om[i] = b_off[co];
}

// x[b][c][4096] -> xt[b][cc][pix][cl]  (fp32 chunk-NHWC, cc = c/32, cl = c%32)
__global__ __launch_bounds__(256) void k_tr_x(const float* __restrict__ x,
                                              float* __restrict__ xt) {
    const int t = threadIdx.x;
    const int pg = blockIdx.x & 15;              // 256-pixel group
    const int cc = (blockIdx.x >> 4) & 7;
    const int b = blockIdx.x >> 7;               // grid 1024
    const int pix = (pg << 8) + t;
    const float* xp = x + ((size_t)b << 20) + ((size_t)(cc << 5) << 12) + pix;
    float v[32];
#pragma unroll
    for (int cl = 0; cl < 32; ++cl) v[cl] = xp[(size_t)cl << 12];
    float* op = xt + ((size_t)b << 20) + ((size_t)cc << 17) + ((size_t)pix << 5);
#pragma unroll
    for (int i = 0; i < 8; ++i)
        *(f32x4*)(op + i * 4) = *(const f32x4*)&v[i * 4];
}

// ---------------- offset conv partial: 8 c-chunks, atomicAdd into om ---------
__global__ __launch_bounds__(256) void k_offset_conv_part(
    const float* __restrict__ x, const float* __restrict__ wofft,
    float* __restrict__ om)
{
    const int t = threadIdx.x;
    const int chunk = blockIdx.x & 7;
    const int rg = (blockIdx.x >> 3) & 15;
    const int b = blockIdx.x >> 7;
    const int h = (rg << 2) + (t >> 6);
    const int w = t & 63;
    const int c0 = chunk << 5;
    const float* xb = x + ((size_t)b << 20);
    float acc[27];
#pragma unroll
    for (int i = 0; i < 27; ++i) acc[i] = 0.f;
    for (int cl = 0; cl < 32; ++cl) {
        const int c = c0 + cl;
        const float* xc = xb + (c << 12);
        float xv[9];
#pragma unroll
        for (int tr = 0; tr < 3; ++tr) {
            int hh = h + tr - 1;
            bool vy = (unsigned)hh < 64u;
#pragma unroll
            for (int tc = 0; tc < 3; ++tc) {
                int ww = w + tc - 1;
                xv[tr * 3 + tc] = (vy && (unsigned)ww < 64u) ? xc[(hh << 6) + ww] : 0.f;
            }
        }
        const float* wc = wofft + c * 243;
#pragma unroll
        for (int co = 0; co < 27; ++co)
#pragma unroll
            for (int k = 0; k < 9; ++k)
                acc[co] = fmaf(xv[k], wc[co * 9 + k], acc[co]);
    }
    float* omb = om + (size_t)b * 110592 + (h << 6) + w;
#pragma unroll
    for (int co = 0; co < 27; ++co)
        atomicAdd(&omb[co << 12], acc[co]);
}

// ---------------- bilinear coeff prep (packed: 4x u16 idx + 4x bf16 wgt) ------
__global__ __launch_bounds__(256) void k_prep_coeff(
    const float* __restrict__ om, uint4* __restrict__ cpk)
{
    int i = blockIdx.x * 256 + threadIdx.x;      // 294912
    int pix = i & 4095;
    int bk = i >> 12;
    int k = bk % 9;
    int b = bk / 9;
    int h = pix >> 6, w = pix & 63;
    const float* omb = om + (size_t)b * 110592;
    float dy = omb[(k << 12) + pix];
    float dx = omb[((9 + k) << 12) + pix];
    float mr = omb[((18 + k) << 12) + pix];
    float m  = 1.f / (1.f + __expf(-mr));
    float py = dy + (float)(k / 3 - 1 + h);
    float px = dx + (float)(k % 3 - 1 + w);
    float y0f = floorf(py), x0f = floorf(px);
    float wy = py - y0f, wx = px - x0f;
    int y0 = (int)y0f, x0 = (int)x0f;
    int y1 = y0 + 1, x1 = x0 + 1;
    float vy0 = ((unsigned)y0 < 64u) ? 1.f : 0.f;
    float vy1 = ((unsigned)y1 < 64u) ? 1.f : 0.f;
    float vx0 = ((unsigned)x0 < 64u) ? 1.f : 0.f;
    float vx1 = ((unsigned)x1 < 64u) ? 1.f : 0.f;
    int cy0 = min(max(y0, 0), 63), cy1 = min(max(y1, 0), 63);
    int cx0 = min(max(x0, 0), 63), cx1 = min(max(x1, 0), 63);
    u32 xw = (u32)((cy0 << 6) + cx0) | ((u32)((cy0 << 6) + cx1) << 16);
    u32 yw = (u32)((cy1 << 6) + cx0) | ((u32)((cy1 << 6) + cx1) << 16);
    float w00 = m * (1.f - wy) * (1.f - wx) * vy0 * vx0;
    float w01 = m * (1.f - wy) * wx         * vy0 * vx1;
    float w10 = m * wy         * (1.f - wx) * vy1 * vx0;
    float w11 = m * wy         * wx         * vy1 * vx1;
    u32 zw = bfr(w00) | (bfr(w01) << 16);
    u32 ww2 = bfr(w10) | (bfr(w11) << 16);
    cpk[i] = make_uint4(xw, yw, zw, ww2);
}

// ---------------- deform conv MFMA GEMM + BN1 + ReLU -> y ----------------
// Double-buffered, pipelined: iter ch issues gathers + A-tile load_lds for
// ch+1 before its MFMA, packs+writes sB after; one barrier per iter.
__global__ __launch_bounds__(256, 2) void k_deform_mfma(
    const float* __restrict__ xt, const u16* __restrict__ Wdb,
    const uint4* __restrict__ cpk, const float* __restrict__ bnp,
    float* __restrict__ yout)
{
    __shared__ __align__(16) u16 sA[2][256 * 40];
    __shared__ __align__(16) u16 sB[2][64 * 40];
    const int t = threadIdx.x;
    const int row = blockIdx.x & 63;
    const int b = blockIdx.x >> 6;
    const int pix0 = row << 6;
    const int p = t >> 2;        // gather pixel 0..63
    const int g = t & 3;         // c subgroup (8 channels each)
    const float* xtb = xt + ((size_t)b << 20);   // [cc][4096][32]

    const int lane = t & 63;
    const int wv = t >> 6;
    const int quad = lane >> 4;
    const int ln = lane & 15;

    f32x4 acc[4][4];
#pragma unroll
    for (int i = 0; i < 4; ++i)
#pragma unroll
        for (int j = 0; j < 4; ++j) acc[i][j] = (f32x4)0.f;

    // prologue: stage iter 0 (k=0, chunk 0) into buffer 0
    uint4 qcur = cpk[(size_t)(b * 9) * 4096 + pix0 + p];
    {
        const float* p00 = xtb + ((size_t)(qcur.x & 0xFFFFu) << 5) + (g << 3);
        const float* p01 = xtb + ((size_t)(qcur.x >> 16) << 5) + (g << 3);
        const float* p10 = xtb + ((size_t)(qcur.y & 0xFFFFu) << 5) + (g << 3);
        const float* p11 = xtb + ((size_t)(qcur.y >> 16) << 5) + (g << 3);
        f32x4 ga[8];
        ga[0] = *(const f32x4*)p00; ga[1] = *(const f32x4*)(p00 + 4);
        ga[2] = *(const f32x4*)p01; ga[3] = *(const f32x4*)(p01 + 4);
        ga[4] = *(const f32x4*)p10; ga[5] = *(const f32x4*)(p10 + 4);
        ga[6] = *(const f32x4*)p11; ga[7] = *(const f32x4*)(p11 + 4);
        const float w00 = __uint_as_float(qcur.z << 16);
        const float w01 = __uint_as_float(qcur.z & 0xFFFF0000u);
        const float w10 = __uint_as_float(qcur.w << 16);
        const float w11 = __uint_as_float(qcur.w & 0xFFFF0000u);
        float v[8];
#pragma unroll
        for (int jj = 0; jj < 4; ++jj) {
            v[jj]     = fmaf(w00, ga[0][jj], fmaf(w01, ga[2][jj], fmaf(w10, ga[4][jj], w11 * ga[6][jj])));
            v[4 + jj] = fmaf(w00, ga[1][jj], fmaf(w01, ga[3][jj], fmaf(w10, ga[5][jj], w11 * ga[7][jj])));
        }
        *(uint4*)&sB[0][p * 40 + g * 8] = make_uint4(
            bfr(v[0]) | (bfr(v[1]) << 16), bfr(v[2]) | (bfr(v[3]) << 16),
            bfr(v[4]) | (bfr(v[5]) << 16), bfr(v[6]) | (bfr(v[7]) << 16));
#pragma unroll
        for (int i = 0; i < 5; ++i)
            load_lds16(Wdb + i * 2048 + t * 8, (char*)sA[0] + i * 4096 + t * 16);
        __syncthreads();
    }

    for (int k = 0; k < 9; ++k) {
        uint4 qnext = qcur;
        if (k < 8) qnext = cpk[(size_t)(b * 9 + k + 1) * 4096 + pix0 + p];
#pragma unroll
        for (int cc = 0; cc < 8; ++cc) {
            const int ch = k * 8 + cc;
            const bool pre = ch < 71;
            const uint4 q = (cc == 7) ? qnext : qcur;   // static select (unrolled)
            f32x4 ga[8];
            if (pre) {
                // issue gathers for iter ch+1 (chunk (cc+1)&7, tap q)
                const float* cb2 = xtb + ((size_t)((cc + 1) & 7) << 17);
                const float* p00 = cb2 + ((size_t)(q.x & 0xFFFFu) << 5) + (g << 3);
                const float* p01 = cb2 + ((size_t)(q.x >> 16) << 5) + (g << 3);
                const float* p10 = cb2 + ((size_t)(q.y & 0xFFFFu) << 5) + (g << 3);
                const float* p11 = cb2 + ((size_t)(q.y >> 16) << 5) + (g << 3);
                ga[0] = *(const f32x4*)p00; ga[1] = *(const f32x4*)(p00 + 4);
                ga[2] = *(const f32x4*)p01; ga[3] = *(const f32x4*)(p01 + 4);
                ga[4] = *(const f32x4*)p10; ga[5] = *(const f32x4*)(p10 + 4);
                ga[6] = *(const f32x4*)p11; ga[7] = *(const f32x4*)(p11 + 4);
                // issue next A tile into the other buffer
                const u16* gA = Wdb + (ch + 1) * 10240;
#pragma unroll
                for (int i = 0; i < 5; ++i)
                    load_lds16(gA + i * 2048 + t * 8,
                               (char*)sA[(cc & 1) ^ 1] + i * 4096 + t * 16);
            }
            // MFMA on current buffer
            bf16x8 af[4], bg[4];
#pragma unroll
            for (int i = 0; i < 4; ++i) {
                af[i] = *(const bf16x8*)&sA[cc & 1][(wv * 64 + i * 16 + ln) * 40 + quad * 8];
                bg[i] = *(const bf16x8*)&sB[cc & 1][(i * 16 + ln) * 40 + quad * 8];
            }
#pragma unroll
            for (int mi = 0; mi < 4; ++mi)
#pragma unroll
                for (int ni = 0; ni < 4; ++ni)
                    acc[mi][ni] = __builtin_amdgcn_mfma_f32_16x16x32_bf16(
                        af[mi], bg[ni], acc[mi][ni], 0, 0, 0);
            if (pre) {
                const float w00 = __uint_as_float(q.z << 16);
                const float w01 = __uint_as_float(q.z & 0xFFFF0000u);
                const float w10 = __uint_as_float(q.w << 16);
                const float w11 = __uint_as_float(q.w & 0xFFFF0000u);
                float v[8];
#pragma unroll
                for (int jj = 0; jj < 4; ++jj) {
                    v[jj]     = fmaf(w00, ga[0][jj], fmaf(w01, ga[2][jj], fmaf(w10, ga[4][jj], w11 * ga[6][jj])));
                    v[4 + jj] = fmaf(w00, ga[1][jj], fmaf(w01, ga[3][jj], fmaf(w10, ga[5][jj], w11 * ga[7][jj])));
                }
                *(uint4*)&sB[(cc & 1) ^ 1][p * 40 + g * 8] = make_uint4(
                    bfr(v[0]) | (bfr(v[1]) << 16), bfr(v[2]) | (bfr(v[3]) << 16),
                    bfr(v[4]) | (bfr(v[5]) << 16), bfr(v[6]) | (bfr(v[7]) << 16));
            }
            __syncthreads();
        }
        qcur = qnext;
    }

    const float* sc1 = bnp;
    const float* bi1 = bnp + 256;
    float* yb2 = yout + ((size_t)b << 20);
#pragma unroll
    for (int mi = 0; mi < 4; ++mi) {
#pragma unroll
        for (int r = 0; r < 4; ++r) {
            int o = wv * 64 + mi * 16 + quad * 4 + r;
            float sc = sc1[o], bi = bi1[o];
#pragma unroll
            for (int ni = 0; ni < 4; ++ni) {
                float v = fmaxf(fmaf(acc[mi][ni][r], sc, bi), 0.f);
                yb2[((size_t)o << 12) + pix0 + ni * 16 + ln] = v;
            }
        }
    }
}

// ---------------- deconv MFMA GEMM + BN2 + ReLU -> up ----------------
// Same double-buffered pipeline: one barrier per K-chunk, next-iter y loads
// + A-tile load_lds issued before MFMA.
__global__ __launch_bounds__(256, 2) void k_deconv_mfma(
    const float* __restrict__ y, const u16* __restrict__ Wtb,
    const float* __restrict__ bnp, float* __restrict__ up)
{
    __shared__ __align__(16) u16 sA[2][256 * 40];
    __shared__ __align__(16) u16 sB[2][64 * 40];
    const int t = threadIdx.x;
    const int h0 = blockIdx.x & 63;
    const int cls = (blockIdx.x >> 6) & 3;
    const int b = blockIdx.x >> 8;
    const int ca = cls >> 1, cb = cls & 1;
    const int DH0 = ca ? 0 : -1, DH1 = ca ? 1 : 0;
    const int DW0 = cb ? 0 : -1, DW1 = cb ? 1 : 0;
    const float* yb = y + ((size_t)b << 20);
    const int p = t >> 2, g = t & 3;

    const int lane = t & 63;
    const int wv = t >> 6;
    const int quad = lane >> 4;
    const int ln = lane & 15;

    // static per-tap offsets/validity (tap = j&3 for kk = g*8+j)
    int tb[4]; float tv[4];
#pragma unroll
    for (int tap = 0; tap < 4; ++tap) {
        int hh = h0 + ((tap >> 1) ? DH1 : DH0);
        int ww = p + ((tap & 1) ? DW1 : DW0);
        bool ok = ((unsigned)hh < 64u) && ((unsigned)ww < 64u);
        tb[tap] = ok ? ((hh << 6) + ww) : 0;
        tv[tap] = ok ? 1.f : 0.f;
    }
    const int g2 = g * 2;
    const u16* WtbC = Wtb + (size_t)cls * 32 * 10240;

    f32x4 acc[4][4];
#pragma unroll
    for (int i = 0; i < 4; ++i)
#pragma unroll
        for (int j = 0; j < 4; ++j) acc[i][j] = (f32x4)0.f;

    // prologue: stage cc=0 into buffer 0
    {
        float yr[8];
#pragma unroll
        for (int j = 0; j < 8; ++j)
            yr[j] = yb[((size_t)(g2 + (j >> 2)) << 12) + tb[j & 3]];
        u32 pk[4];
#pragma unroll
        for (int j = 0; j < 8; ++j) {
            u32 bv = bfr(yr[j] * tv[j & 3]);
            if ((j & 1) == 0) pk[j >> 1] = bv; else pk[j >> 1] |= bv << 16;
        }
        *(uint4*)&sB[0][p * 40 + g * 8] = *(const uint4*)pk;
#pragma unroll
        for (int i = 0; i < 5; ++i)
            load_lds16(WtbC + i * 2048 + t * 8, (char*)sA[0] + i * 4096 + t * 16);
        __syncthreads();
    }

#pragma unroll 2
    for (int cc = 0; cc < 32; ++cc) {
        const int buf = cc & 1;
        const bool pre = cc < 31;
        float yr[8];
        if (pre) {
            const int c8 = (cc + 1) * 8;
#pragma unroll
            for (int j = 0; j < 8; ++j)
                yr[j] = yb[((size_t)(c8 + g2 + (j >> 2)) << 12) + tb[j & 3]];
            const u16* gA = WtbC + (size_t)(cc + 1) * 10240;
#pragma unroll
            for (int i = 0; i < 5; ++i)
                load_lds16(gA + i * 2048 + t * 8,
                           (char*)sA[buf ^ 1] + i * 4096 + t * 16);
        }
        bf16x8 af[4], bg[4];
#pragma unroll
        for (int i = 0; i < 4; ++i) {
            af[i] = *(const bf16x8*)&sA[buf][(wv * 64 + i * 16 + ln) * 40 + quad * 8];
            bg[i] = *(const bf16x8*)&sB[buf][(i * 16 + ln) * 40 + quad * 8];
        }
#pragma unroll
        for (int mi = 0; mi < 4; ++mi)
#pragma unroll
            for (int ni = 0; ni < 4; ++ni)
                acc[mi][ni] = __builtin_amdgcn_mfma_f32_16x16x32_bf16(
                    af[mi], bg[ni], acc[mi][ni], 0, 0, 0);
        if (pre) {
            u32 pk[4];
#pragma unroll
            for (int j = 0; j < 8; ++j) {
                u32 bv = bfr(yr[j] * tv[j & 3]);
                if ((j & 1) == 0) pk[j >> 1] = bv; else pk[j >> 1] |= bv << 16;
            }
            *(uint4*)&sB[buf ^ 1][p * 40 + g * 8] = *(const uint4*)pk;
        }
        __syncthreads();
    }

    const float* sc2 = bnp + 512;
    const float* bi2 = bnp + 768;
    float* ub = up + ((size_t)b << 22);
    const int pr = (h0 << 1) + ca;
#pragma unroll
    for (int mi = 0; mi < 4; ++mi) {
#pragma unroll
        for (int r = 0; r < 4; ++r) {
            int o = wv * 64 + mi * 16 + quad * 4 + r;
            float sc = sc2[o], bi = bi2[o];
#pragma unroll
            for (int ni = 0; ni < 4; ++ni) {
                int qc = ((ni * 16 + ln) << 1) + cb;
                float v = fmaxf(fmaf(acc[mi][ni][r], sc, bi), 0.f);
                ub[((size_t)o << 14) + (pr << 7) + qc] = v;
            }
        }
    }
}

extern "C" void kernel_launch(void* const* d_in, const int* in_sizes, int n_in,
                              void* d_out, int out_size, void* d_ws, size_t ws_size,
                              hipStream_t stream)
{
    const float* x     = (const float*)d_in[0];
    const float* w_off = (const float*)d_in[1];
    const float* b_off = (const float*)d_in[2];
    const float* w_dcn = (const float*)d_in[3];
    const float* g1    = (const float*)d_in[4];
    const float* be1   = (const float*)d_in[5];
    const float* mu1   = (const float*)d_in[6];
    const float* va1   = (const float*)d_in[7];
    const float* w_up  = (const float*)d_in[8];
    const float* g2    = (const float*)d_in[9];
    const float* be2   = (const float*)d_in[10];
    const float* mu2   = (const float*)d_in[11];
    const float* va2   = (const float*)d_in[12];

    float* yout = (float*)d_out;                 // 8*256*64*64
    float* up   = (float*)d_out + 8388608;       // 8*256*128*128
    // xt scratch lives in the 'up' region (33.5 MB of its 134 MB); it is
    // consumed by k_deform_mfma and fully overwritten later by k_deconv_mfma.
    float* xt   = up;

    char* ws = (char*)d_ws;
    float* om    = (float*)(ws + 0);             // 3,538,944 B
    float* wofft = (float*)(ws + 3538944);       //   248,832 B
    uint4* cpk   = (uint4*)(ws + 3787776);       // 4,718,592 B
    u16*   Wdb   = (u16*)  (ws + 8506368);       // 1,474,560 B
    u16*   Wtb   = (u16*)  (ws + 9980928);       // 2,621,440 B
    float* bnp   = (float*)(ws + 12602368);      //     4,096 B
    // total ws: 12.6 MB

    k_tr_woff   <<<243,  256, 0, stream>>>(w_off, wofft);
    k_prep_wdb  <<<2880, 256, 0, stream>>>(w_dcn, Wdb);
    k_prep_wtb  <<<5120, 256, 0, stream>>>(w_up, Wtb);
    k_bn_prep   <<<1,    256, 0, stream>>>(g1, be1, mu1, va1, g2, be2, mu2, va2, bnp);
    k_om_init   <<<3456, 256, 0, stream>>>(b_off, om);
    k_tr_x      <<<1024, 256, 0, stream>>>(x, xt);
    k_offset_conv_part<<<1024, 256, 0, stream>>>(x, wofft, om);
    k_prep_coeff<<<1152, 256, 0, stream>>>(om, cpk);
    k_deform_mfma<<<512, 256, 0, stream>>>(xt, Wdb, cpk, bnp, yout);
    k_deconv_mfma<<<2048,256, 0, stream>>>(yout, Wtb, bnp, up);
}